// Round 7
// baseline (37.545 us; speedup 1.0000x reference)
//
#include <hip/hip_runtime.h>

#define N_LAYERS 512
#define DEL_Z (0.9f / 512.0f)
#define NGROUP (N_LAYERS / 4)     // 128 groups of 4 layers

// Exact-algebra refactor of the reference step, carrying t = Re + inv1(l):
//   e  = c0 + 2*DEL_Z*om*Im
//   u  = e*t + d1                      ( = Rn + inv1(l) )
//   Im'= c0*Im + DEL_Z*om*(Im^2 - u^2 + 1/b1^2) - (DEL_Z*z^2/b1)/om
//   t' = u + dl
// KEY IDENTITY: inv2/PiT == inv1^2, so the reference's c3 collapses to 1/b1^2
// (pure-b). Pure-z terms are generated per-thread by a Taylor-3 reciprocal
// chain on y ~= inv1 (y' = y + inc, inc = p(1+q+q^2), q = DEL_Z*y, p = q*y):
//   d1 = -DEL_Z*PiT*y^2 = -PiT*p        (exact given y)
//   dl = inc                            (rel err q^3; sum ~1.6e-4 — benign)
// y-drift cancels EXACTLY in Re since t - y == Re by construction.
// Broadcast constants: just {c0 = 2-b2/b1, c4p = DEL_Z*z^2/b1, r1 = 1/b1}
// -> 12 B/layer/lane on the LDS return bus (R1/R5 were bus-bound at 20 B).

#define STEP(C0, C4P, R1)                                       \
    {                                                           \
        const float q   = DEL_Z * y;                            \
        const float p   = q * y;                                \
        const float w   = fmaf(q, p, p);                        \
        const float inc = fmaf(q, w, p);                        \
        const float d1  = p * nPiT;                             \
        y += inc;                                               \
        const float r2  = (R1) * (R1);                          \
        const float q4  = (C4P) * niom;                         \
        const float e   = fmaf(dz2om, Im, (C0));                \
        const float u   = fmaf(e, t, d1);                       \
        float s = fmaf(Im, Im, r2);                             \
        s = fmaf(-u, u, s);                                     \
        const float b   = fmaf((C0), Im, q4);                   \
        Im = fmaf(dzom, s, b);                                  \
        t  = u + inc;                                           \
    }

#define GROUP4(A0, A1, A2)                                      \
    STEP((A0).x, (A1).x, (A2).x)                                \
    STEP((A0).y, (A1).y, (A2).y)                                \
    STEP((A0).z, (A1).z, (A2).z)                                \
    STEP((A0).w, (A1).w, (A2).w)

#define LOADG(A0, A1, A2, G)                                    \
    {                                                           \
        const float4* cp = cg[(G)];                             \
        (A0) = cp[0]; (A1) = cp[1]; (A2) = cp[2];               \
    }

__global__ __launch_bounds__(256) void metric_scan_kernel(
    const float* __restrict__ Re_s, const float* __restrict__ Im_s,
    const float* __restrict__ omega, const float* __restrict__ PiT_p,
    const float* __restrict__ B, float* __restrict__ out, int n)
{
    // [group][0]=c0 x4, [1]=c4p x4, [2]=r1 x4   (4 layers per group, 48 B)
    __shared__ float4 cg[NGROUP][3];   // 6144 B

    const float PiT = PiT_p[0];
    float* cbase = (float*)cg;
    for (int l = threadIdx.x; l < N_LAYERS; l += 256) {
        const float z  = DEL_Z * (float)l;    // Z_INI == 0
        const float b1 = B[l];
        const float b2 = B[l + 1];
        float* p = cbase + (l >> 2) * 12 + (l & 3);
        p[0] = 2.0f - b2 / b1;                // c0 = 1 + g
        p[4] = DEL_Z * z * z / b1;            // c4p   (MU^2 == 1)
        p[8] = 1.0f / b1;                     // r1
    }
    __syncthreads();

    const int i = blockIdx.x * 256 + threadIdx.x;
    float Im = Im_s[i];
    const float om    = omega[i];
    const float dzom  = DEL_Z * om;
    const float dz2om = 2.0f * dzom;
    const float niom  = -1.0f / om;
    const float nPiT  = -PiT;
    float y = 1.0f / PiT;                     // y_0 = inv1(z=0)
    float t = Re_s[i] + y;                    // t_0 = Re + inv1(0)

    // Register double-buffer: load group g+1 while computing group g.
    float4 Pa0, Pa1, Pa2, Pb0, Pb1, Pb2;
    LOADG(Pa0, Pa1, Pa2, 0);

    for (int g = 0; g < NGROUP; g += 2) {
        LOADG(Pb0, Pb1, Pb2, g + 1);
        GROUP4(Pa0, Pa1, Pa2);
        const int gn = (g + 2 < NGROUP) ? g + 2 : NGROUP - 1;  // clamp, no OOB
        LOADG(Pa0, Pa1, Pa2, gn);
        GROUP4(Pb0, Pb1, Pb2);
    }

    out[i]     = t - y;       // Re_f: y-chain drift cancels exactly
    out[n + i] = Im;
}

extern "C" void kernel_launch(void* const* d_in, const int* in_sizes, int n_in,
                              void* d_out, int out_size, void* d_ws, size_t ws_size,
                              hipStream_t stream)
{
    const float* Re_s  = (const float*)d_in[0];
    const float* Im_s  = (const float*)d_in[1];
    const float* omega = (const float*)d_in[2];
    const float* PiT   = (const float*)d_in[3];
    const float* B     = (const float*)d_in[4];
    float* out = (float*)d_out;
    const int n = in_sizes[0];                  // 131072
    metric_scan_kernel<<<n / 256, 256, 0, stream>>>(Re_s, Im_s, omega, PiT, B, out, n);
}

// Round 8
// 25.062 us; speedup vs baseline: 1.4981x; 1.4981x over previous
//
#include <hip/hip_runtime.h>

#define N_LAYERS 512
#define DEL_Z (0.9f / 512.0f)
#define INV_DEL_Z (512.0f / 0.9f)
#define NGROUP (N_LAYERS / 4)     // 128 groups of 4 layers

// Exact-algebra refactor, carrying t = Re + inv1(l)  (validated form, R7: absmax 0.0625):
//   e  = c0 + 2*DEL_Z*om*Im
//   u  = e*t + d1                       ( = Rn + inv1(l) )
//   Im'= c0*Im + DEL_Z*om*(Im^2 - u^2 + c3 + c4p*phi)
//   t' = u + dl
// Identities: inv2/PiT == inv1^2  =>  reference c3 collapses to 1/b1^2
//             inv2 == inv1^2*PiT  (used in setup)
// Per-layer LDS constants {c0, d1, dl, c3, c4p} (20 B), all EXACT (no per-thread
// reciprocal chain — R4/R7's serial-chain formulations were the anomalies):
//   c0 = 2 - b2/b1, d1 = -DEL_Z*inv2, dl = inv1(l+1)-inv1(l), c3 = 1/b1^2,
//   c4p = DEL_Z*z^2/b1;  thread const phi = -1/(DEL_Z*om^2).
// 8 VALU ops/layer (R5 had 10). Distance-2 LDS prefetch via 4 rotating
// register buffers: loads issue ~128 cy before first use.

#define STEP(C0, D1, DL, C3, C4P)                               \
    {                                                           \
        const float e  = fmaf(dz2om, Im, (C0));                 \
        const float u  = fmaf(e, t, (D1));                      \
        float s = fmaf(Im, Im, (C3));                           \
        const float bm = (C0) * Im;                             \
        s = fmaf(-u, u, s);                                     \
        s = fmaf((C4P), phi, s);                                \
        Im = fmaf(dzom, s, bm);                                 \
        t  = u + (DL);                                          \
    }

#define GROUP4(A0, A1, A2, A3, A4)                              \
    STEP((A0).x, (A1).x, (A2).x, (A3).x, (A4).x)                \
    STEP((A0).y, (A1).y, (A2).y, (A3).y, (A4).y)                \
    STEP((A0).z, (A1).z, (A2).z, (A3).z, (A4).z)                \
    STEP((A0).w, (A1).w, (A2).w, (A3).w, (A4).w)

#define LOADG(A0, A1, A2, A3, A4, G)                            \
    {                                                           \
        const float4* cp = cg[(G)];                             \
        (A0) = cp[0]; (A1) = cp[1]; (A2) = cp[2];               \
        (A3) = cp[3]; (A4) = cp[4];                             \
    }

__global__ __launch_bounds__(256) void metric_scan_kernel(
    const float* __restrict__ Re_s, const float* __restrict__ Im_s,
    const float* __restrict__ omega, const float* __restrict__ PiT_p,
    const float* __restrict__ B, float* __restrict__ out, int n)
{
    // [group][0]=c0 x4, [1]=d1 x4, [2]=dl x4, [3]=c3 x4, [4]=c4p x4
    __shared__ float4 cg[NGROUP][5];   // 10240 B

    const float PiT = PiT_p[0];
    float* cbase = (float*)cg;
    for (int l = threadIdx.x; l < N_LAYERS; l += 256) {
        const float z     = DEL_Z * (float)l;          // Z_INI == 0
        const float zn    = DEL_Z * (float)(l + 1);
        const float b1    = B[l];
        const float b2    = B[l + 1];
        const float inv1  = 1.0f / (PiT * (1.0f - z));
        const float inv1n = 1.0f / (PiT * (1.0f - zn));
        const float inv2  = inv1 * inv1 * PiT;         // exact identity
        float* p = cbase + (l >> 2) * 20 + (l & 3);
        p[0]  = 2.0f - b2 / b1;                        // c0
        p[4]  = -DEL_Z * inv2;                         // d1
        p[8]  = inv1n - inv1;                          // dl
        p[12] = 1.0f / (b1 * b1);                      // c3
        p[16] = DEL_Z * z * z / b1;                    // c4p  (MU^2 == 1)
    }
    __syncthreads();

    const int i = blockIdx.x * 256 + threadIdx.x;
    float Im = Im_s[i];
    const float om    = omega[i];
    const float dzom  = DEL_Z * om;
    const float dz2om = 2.0f * dzom;
    const float iom   = 1.0f / om;
    const float phi   = -(iom * iom) * INV_DEL_Z;      // c4p*phi == c4p*(-1/om)/dzom
    float t = Re_s[i] + 1.0f / PiT;                    // t_0 = Re + inv1(0)

    float4 Pa0, Pa1, Pa2, Pa3, Pa4;
    float4 Pb0, Pb1, Pb2, Pb3, Pb4;
    float4 Pc0, Pc1, Pc2, Pc3, Pc4;
    float4 Pd0, Pd1, Pd2, Pd3, Pd4;

    LOADG(Pa0, Pa1, Pa2, Pa3, Pa4, 0);
    LOADG(Pb0, Pb1, Pb2, Pb3, Pb4, 1);

    #pragma unroll 1
    for (int it = 0; it < NGROUP / 4; ++it) {
        const int g  = 4 * it;
        const int g2 = (g + 2 < NGROUP) ? g + 2 : NGROUP - 1;
        const int g3 = (g + 3 < NGROUP) ? g + 3 : NGROUP - 1;
        const int g4 = (g + 4 < NGROUP) ? g + 4 : NGROUP - 1;
        const int g5 = (g + 5 < NGROUP) ? g + 5 : NGROUP - 1;
        LOADG(Pc0, Pc1, Pc2, Pc3, Pc4, g2);
        GROUP4(Pa0, Pa1, Pa2, Pa3, Pa4);               // group g
        LOADG(Pd0, Pd1, Pd2, Pd3, Pd4, g3);
        GROUP4(Pb0, Pb1, Pb2, Pb3, Pb4);               // group g+1
        LOADG(Pa0, Pa1, Pa2, Pa3, Pa4, g4);
        GROUP4(Pc0, Pc1, Pc2, Pc3, Pc4);               // group g+2
        LOADG(Pb0, Pb1, Pb2, Pb3, Pb4, g5);
        GROUP4(Pd0, Pd1, Pd2, Pd3, Pd4);               // group g+3
    }

    // Re_f = t_final - inv1(z=0.9);  (1 - 0.9) = 0.1
    const float Re_f = t - 1.0f / (PiT * 0.1f);

    out[i]     = Re_f;
    out[n + i] = Im;
}

extern "C" void kernel_launch(void* const* d_in, const int* in_sizes, int n_in,
                              void* d_out, int out_size, void* d_ws, size_t ws_size,
                              hipStream_t stream)
{
    const float* Re_s  = (const float*)d_in[0];
    const float* Im_s  = (const float*)d_in[1];
    const float* omega = (const float*)d_in[2];
    const float* PiT   = (const float*)d_in[3];
    const float* B     = (const float*)d_in[4];
    float* out = (float*)d_out;
    const int n = in_sizes[0];                  // 131072
    metric_scan_kernel<<<n / 256, 256, 0, stream>>>(Re_s, Im_s, omega, PiT, B, out, n);
}